// Round 15
// baseline (144.106 us; speedup 1.0000x reference)
//
#include <hip/hip_runtime.h>

#define D_MODEL 1024
#define D_INNER 2048
#define N_ST    16
#define DT_RANK 64
#define BSZ     2
#define SEQL    1024
#define NTOK    (BSZ*SEQL)   // 2048
#define NC      32           // scan chunks
#define LC      (SEQL/NC)    // 32 steps per chunk

typedef __attribute__((ext_vector_type(4))) float f32x4;
typedef __attribute__((ext_vector_type(8))) short bf16x8;

__device__ __forceinline__ short f2b(float f) {
  unsigned u = __builtin_bit_cast(unsigned, f);
  u += 0x7fffu + ((u >> 16) & 1u);           // round-to-nearest-even
  return (short)(u >> 16);
}

__device__ __forceinline__ float b2f(unsigned short s) {
  return __builtin_bit_cast(float, (unsigned)s << 16);
}

__device__ __forceinline__ void gload16(const void* g, void* l) {
  __builtin_amdgcn_global_load_lds(
      (const __attribute__((address_space(1))) void*)g,
      (__attribute__((address_space(3))) void*)l, 16, 0, 0);
}

// C[M,N] = epi(A[M,K] @ B[N,K]^T + bias); A,B bf16 (B pre-transposed [N][K]).
// 128x128 tile, BK=32, 48 KB LDS (3-deep rotation x 8KB x {A,B}).
// ONE barrier per K-step: STAGE(t+1 -> buf[(t+1)%3]) -> vmcnt(4) -> barrier ->
// MFMA(buf[t%3]). 3-deep rotation makes the post-MFMA barrier unnecessary:
// max wave skew is 1 iter (barrier-enforced), so STAGE(t+2) writes a buffer
// disjoint from both live read buffers (t%3, (t+1)%3). Swizzle: granule
// g' = g ^ ((row>>1)&3) on both source address and ds_read (2-way = free).
// PARTIAL: 1 = fp32 partials at z*M*ldc; 2 = bf16 partials.
// RESSPLIT (GEMM1): XCD-chunked y-major remap; cols<2048 -> u_pre: boundary
//   rows to upb, fused conv+silu rows 2..127 to ubuf (via 32KB LDS tile);
//   cols>=2048 -> silu bf16 to resb.
// OUTB16: store epi result bf16 to upb at ldc stride.
// FIXUP (GEMM2): prologue finishes conv+silu for this block's 2 boundary
//   tokens x its 128-d slice (A region), writing ubuf before staging.
template<int SOFTPLUS, int PARTIAL, int RESSPLIT, int OUTB16, int FIXUP>
__global__ __launch_bounds__(256)
void gemm_kernel(const short* __restrict__ A, const short* __restrict__ Bm,
                 const float* __restrict__ bias, float* __restrict__ C,
                 short* __restrict__ upb, short* __restrict__ resb,
                 const float* __restrict__ cw, const float* __restrict__ cb,
                 short* __restrict__ ubuf,
                 int M, int N, int K, int lda, int ldb, int ldc, int kChunk)
{
  __shared__ short lds[24576];   // 48 KB: A bufs 0/4096/8192; B bufs +12288
  const int tid  = threadIdx.x;
  const int lane = tid & 63;
  const int wave = tid >> 6;
  const int wr = wave >> 1, wc = wave & 1;
  const int lr = lane & 15, lg = lane >> 4;

  int bx = blockIdx.x, by = blockIdx.y;
  if (RESSPLIT) {   // grid (32,16): XCD-chunked, y-major within XCD
    const int lin = by * 32 + bx;
    const int lb = (lin & 7) * 64 + (lin >> 3);
    bx = lb >> 4; by = lb & 15;
  }
  const int m0 = by * 128;
  const int n0 = bx * 128;
  const int kStart = blockIdx.z * kChunk;
  int kEnd = kStart + kChunk; if (kEnd > K) kEnd = K;
  const int nt = (kEnd - kStart) >> 5;   // BK=32 steps

  if (FIXUP) {
    // finish conv+silu for boundary tokens {m0, m0+1} x d-slice [kStart,+128)
    const int tt = m0 + (tid >> 7);
    const int dd = kStart + (tid & 127);
    const int l  = tt & (SEQL - 1);
    float u2 = b2f((unsigned short)upb[(size_t)tt * 2048 + dd]);
    float u1 = (l >= 1) ? b2f((unsigned short)upb[(size_t)(tt - 1) * 2048 + dd]) : 0.f;
    float u0 = (l >= 2) ? b2f((unsigned short)upb[(size_t)(tt - 2) * 2048 + dd]) : 0.f;
    float r = cb[dd] + cw[dd * 3] * u0 + cw[dd * 3 + 1] * u1 + cw[dd * 3 + 2] * u2;
    ubuf[(size_t)tt * 2048 + dd] = f2b(r / (1.f + __expf(-r)));
    asm volatile("s_waitcnt vmcnt(0)" ::: "memory");  // stores retired to L2
    __syncthreads();                                  // before any gload16 reads them
  }

  // staging: wave covers 32 rows; one gload16 covers 16 rows x 32 k (1 KB).
  // lane -> row = lane>>2, granule = lane&3 (16B). Source granule pre-swizzled
  // by ((row>>1)&3) so LDS (linear) holds G[row][g ^ ((row>>1)&3)] at slot g.
  const int srow = lane >> 2;                          // 0..15
  const int sgran = (lane & 3) ^ ((lane >> 3) & 3);    // (lane&3) ^ ((srow>>1)&3)
  const short* aS = A + (size_t)(m0 + wave * 32 + srow) * lda + sgran * 8 + kStart;
  const short* bS = Bm + (size_t)(n0 + wave * 32 + srow) * ldb + sgran * 8 + kStart;
  const int ldsOff = wave * 1024;                      // wave's 32x32 region (shorts)

#define STAGE(buf, koff)                                                        \
  {                                                                             \
    _Pragma("unroll")                                                           \
    for (int i_ = 0; i_ < 2; ++i_) {                                            \
      gload16(aS + (size_t)(i_ * 16) * lda + (koff),                            \
              &lds[(buf) * 4096 + ldsOff + i_ * 512]);                          \
      gload16(bS + (size_t)(i_ * 16) * ldb + (koff),                            \
              &lds[12288 + (buf) * 4096 + ldsOff + i_ * 512]);                  \
    }                                                                           \
  }

  f32x4 acc[4][4];
#pragma unroll
  for (int i = 0; i < 4; ++i)
#pragma unroll
    for (int j = 0; j < 4; ++j) acc[i][j] = (f32x4){0.f, 0.f, 0.f, 0.f};

  STAGE(0, 0);

  int cur = 0, nxt = 1;
  for (int t = 0; t < nt; ++t) {
    if (t + 1 < nt) {
      STAGE(nxt, (t + 1) * 32);
      asm volatile("s_waitcnt vmcnt(4)" ::: "memory");  // tile-t staged; t+1 in flight
    } else {
      asm volatile("s_waitcnt vmcnt(0)" ::: "memory");
    }
    __builtin_amdgcn_s_barrier();   // buf[cur] visible to all waves

    bf16x8 aF[4], bF[4];
#pragma unroll
    for (int mi = 0; mi < 4; ++mi) {
      const int row = wr * 64 + mi * 16 + lr;
      aF[mi] = *reinterpret_cast<const bf16x8*>(
          &lds[cur * 4096 + row * 32 + ((lg ^ ((row >> 1) & 3)) << 3)]);
    }
#pragma unroll
    for (int ni = 0; ni < 4; ++ni) {
      const int row = wc * 64 + ni * 16 + lr;
      bF[ni] = *reinterpret_cast<const bf16x8*>(
          &lds[12288 + cur * 4096 + row * 32 + ((lg ^ ((row >> 1) & 3)) << 3)]);
    }
#pragma unroll
    for (int mi = 0; mi < 4; ++mi)
#pragma unroll
      for (int ni = 0; ni < 4; ++ni)
        acc[mi][ni] = __builtin_amdgcn_mfma_f32_16x16x32_bf16(
            aF[mi], bF[ni], acc[mi][ni], 0, 0, 0);

    cur = nxt; nxt = (nxt == 2) ? 0 : nxt + 1;   // no post-MFMA barrier (3-deep)
  }
#undef STAGE
  __syncthreads();   // all waves done reading LDS before epilogue reuse

  // epilogue: C/D layout col=lane&15, row=(lane>>4)*4+reg
  if (RESSPLIT) {
    if (n0 < 2048) {
      // u_pre tile -> LDS (first 32KB = 128x128 bf16); boundary rows -> upb
      short (*sU)[128] = reinterpret_cast<short (*)[128]>(&lds[0]);
#pragma unroll
      for (int mi = 0; mi < 4; ++mi) {
#pragma unroll
        for (int ni = 0; ni < 4; ++ni) {
          const int cl = wc * 64 + ni * 16 + lr;
          const float bv = bias[n0 + cl];
#pragma unroll
          for (int j = 0; j < 4; ++j) {
            const int rl = wr * 64 + mi * 16 + lg * 4 + j;
            const short s = f2b(acc[mi][ni][j] + bv);
            sU[rl][cl] = s;
            if (rl < 2 || rl >= 126)
              upb[(size_t)(m0 + rl) * 2048 + (n0 + cl)] = s;
          }
        }
      }
      __syncthreads();
      // fused causal conv(K=3) + bias + silu for rows 2..127
#pragma unroll
      for (int ni = 0; ni < 4; ++ni) {
        const int cl = wc * 64 + ni * 16 + lr;
        const int col = n0 + cl;
        const float w0 = cw[col * 3], w1 = cw[col * 3 + 1], w2 = cw[col * 3 + 2];
        const float cbv = cb[col];
#pragma unroll
        for (int mi = 0; mi < 4; ++mi) {
#pragma unroll
          for (int j = 0; j < 4; ++j) {
            const int rl = wr * 64 + mi * 16 + lg * 4 + j;
            if (rl >= 2) {
              float r = cbv + w0 * b2f((unsigned short)sU[rl - 2][cl])
                            + w1 * b2f((unsigned short)sU[rl - 1][cl])
                            + w2 * b2f((unsigned short)sU[rl][cl]);
              ubuf[(size_t)(m0 + rl) * 2048 + col] = f2b(r / (1.f + __expf(-r)));
            }
          }
        }
      }
    } else {
#pragma unroll
      for (int mi = 0; mi < 4; ++mi) {
        const int row = m0 + wr * 64 + mi * 16 + lg * 4;
#pragma unroll
        for (int ni = 0; ni < 4; ++ni) {
          const int col = n0 + wc * 64 + ni * 16 + lr;
          const float bv = bias[col];
#pragma unroll
          for (int j = 0; j < 4; ++j) {
            float v = acc[mi][ni][j] + bv;
            resb[(size_t)(row + j) * 2048 + (col - 2048)] =
                f2b(v / (1.f + __expf(-v)));
          }
        }
      }
    }
    return;
  }

#pragma unroll
  for (int mi = 0; mi < 4; ++mi) {
    const int row = m0 + wr * 64 + mi * 16 + lg * 4;
#pragma unroll
    for (int ni = 0; ni < 4; ++ni) {
      const int col = n0 + wc * 64 + ni * 16 + lr;
      if (OUTB16) {
        const float bv = bias[col];
#pragma unroll
        for (int j = 0; j < 4; ++j) {
          float v = acc[mi][ni][j] + bv;
          if (SOFTPLUS) v = fmaxf(v, 0.f) + log1pf(__expf(-fabsf(v)));
          upb[(size_t)(row + j) * ldc + col] = f2b(v);
        }
      } else if (PARTIAL == 2) {
        short* Cs = (short*)C + (size_t)blockIdx.z * M * ldc;
#pragma unroll
        for (int j = 0; j < 4; ++j)
          Cs[(size_t)(row + j) * ldc + col] = f2b(acc[mi][ni][j]);
      } else if (col < N) {
        float* Cp = PARTIAL ? C + (size_t)blockIdx.z * M * ldc : C;
        float bv = (bias != nullptr && blockIdx.z == 0) ? bias[col] : 0.f;
#pragma unroll
        for (int j = 0; j < 4; ++j) {
          float v = acc[mi][ni][j] + bv;
          if (SOFTPLUS) v = fmaxf(v, 0.f) + log1pf(__expf(-fabsf(v)));
          Cp[(size_t)(row + j) * ldc + col] = v;
        }
      }
    }
  }
}

// ---- fused prep: castA(x) + transpose-cast of all 4 weights, one dispatch ----
__device__ __forceinline__ void trans_body(const float* __restrict__ in,
                                           short* __restrict__ out,
                                           int R, int C, int bx, int by,
                                           short (*t)[33], int tidx)
{
  const int c0 = bx * 32, r0 = by * 32;
  const int cc = tidx & 31, rr = tidx >> 5;  // rr 0..7
#pragma unroll
  for (int i = 0; i < 4; ++i)
    t[rr + i * 8][cc] = f2b(in[(size_t)(r0 + rr + i * 8) * C + c0 + cc]);
  __syncthreads();
#pragma unroll
  for (int i = 0; i < 4; ++i)
    out[(size_t)(c0 + rr + i * 8) * R + r0 + cc] = t[cc][rr + i * 8];
}

#define PB_CAST  2048
#define PB_WIN   4096
#define PB_WX    192
#define PB_WDT   128
#define PB_WOUT  2048

__global__ __launch_bounds__(256)
void prep_kernel(const float* __restrict__ x,    const float* __restrict__ W_in,
                 const float* __restrict__ W_x,  const float* __restrict__ W_dt,
                 const float* __restrict__ W_out,
                 short* __restrict__ xb,  short* __restrict__ Wib,
                 short* __restrict__ Wxb, short* __restrict__ Wdtb,
                 short* __restrict__ Wob)
{
  __shared__ short t[32][33];
  const int bid = blockIdx.x, tidx = threadIdx.x;
  if (bid < PB_CAST) {
    const int i = bid * 256 + tidx;
    float4 v = *reinterpret_cast<const float4*>(x + (size_t)i * 4);
    *reinterpret_cast<short4*>(xb + (size_t)i * 4) =
        make_short4(f2b(v.x), f2b(v.y), f2b(v.z), f2b(v.w));
  } else if (bid < PB_CAST + PB_WIN) {
    const int b = bid - PB_CAST;
    trans_body(W_in, Wib, 1024, 4096, b % 128, b / 128, t, tidx);
  } else if (bid < PB_CAST + PB_WIN + PB_WX) {
    const int b = bid - PB_CAST - PB_WIN;
    trans_body(W_x, Wxb, 2048, 96, b % 3, b / 3, t, tidx);
  } else if (bid < PB_CAST + PB_WIN + PB_WX + PB_WDT) {
    const int b = bid - PB_CAST - PB_WIN - PB_WX;
    trans_body(W_dt, Wdtb, 64, 2048, b % 64, b / 64, t, tidx);
  } else {
    const int b = bid - PB_CAST - PB_WIN - PB_WX - PB_WDT;
    trans_body(W_out, Wob, 2048, 1024, b % 32, b / 32, t, tidx);
  }
}

// combine 16 split-K partials of GEMM2 -> xp fp32 [2048][96]; dt cols -> dtb bf16
__global__ __launch_bounds__(256)
void combine16_kernel(const float* __restrict__ part, float* __restrict__ xp,
                      short* __restrict__ dtb)
{
  const int gid = blockIdx.x * 256 + threadIdx.x;   // 0 .. 2048*24-1
  const int r = gid / 24, q = gid - r * 24;
  float4 s = make_float4(0.f, 0.f, 0.f, 0.f);
#pragma unroll
  for (int c = 0; c < 16; ++c) {
    const float4 v = *reinterpret_cast<const float4*>(
        part + (size_t)c * 2048 * 96 + (size_t)r * 96 + q * 4);
    s.x += v.x; s.y += v.y; s.z += v.z; s.w += v.w;
  }
  *reinterpret_cast<float4*>(xp + (size_t)r * 96 + q * 4) = s;
  if (q < 16)
    *reinterpret_cast<short4*>(dtb + (size_t)r * 64 + q * 4) =
        make_short4(f2b(s.x), f2b(s.y), f2b(s.z), f2b(s.w));
}

// combine 4 bf16 split-K partials of GEMM4 + bias -> out fp32 [2048][1024]
__global__ __launch_bounds__(256)
void combine4_kernel(const unsigned short* __restrict__ part,
                     const float* __restrict__ bias, float* __restrict__ out)
{
  const int gid = blockIdx.x * 256 + threadIdx.x;   // over 2048*256 float4s
  const int r = gid >> 8, c4 = gid & 255;
  const float4 bv = *reinterpret_cast<const float4*>(bias + c4 * 4);
  float4 s = bv;
#pragma unroll
  for (int z = 0; z < 4; ++z) {
    const ushort4 v = *reinterpret_cast<const ushort4*>(
        part + (size_t)z * 2048 * 1024 + (size_t)r * 1024 + c4 * 4);
    s.x += b2f(v.x); s.y += b2f(v.y); s.z += b2f(v.z); s.w += b2f(v.w);
  }
  *reinterpret_cast<float4*>(out + (size_t)r * 1024 + c4 * 4) = s;
}

// ---- chunked selective scan: thread owns (b, chunk, d) with all 16 n ----
__global__ __launch_bounds__(256, 4)
void scan_pass1(const unsigned short* __restrict__ deltab, const unsigned short* __restrict__ ub,
                const float* __restrict__ xp, const float* __restrict__ A_log,
                float* __restrict__ sdl, float* __restrict__ HS)
{
  const int d = blockIdx.y * 256 + threadIdx.x;
  const int c = blockIdx.x, b = blockIdx.z;
  const int t0 = (b << 10) + c * LC;
  float Ac[16];
#pragma unroll
  for (int q = 0; q < 4; ++q) {
    float4 a = *reinterpret_cast<const float4*>(A_log + (size_t)d * 16 + q * 4);
    Ac[q * 4 + 0] = -__expf(a.x); Ac[q * 4 + 1] = -__expf(a.y);
    Ac[q * 4 + 2] = -__expf(a.z); Ac[q * 4 + 3] = -__expf(a.w);
  }
  float h[16];
#pragma unroll
  for (int n = 0; n < 16; ++n) h[n] = 0.f;
  float sd = 0.f;
  const unsigned short* dp = deltab + (size_t)t0 * 2048 + d;
  const unsigned short* up = ub + (size_t)t0 * 2048 + d;
  const float* xb = xp + (size_t)t0 * 96 + DT_RANK;
#pragma unroll 4
  for (int t = 0; t < LC; ++t) {
    float dl = b2f(dp[(size_t)t * 2048]);
    float ul = b2f(up[(size_t)t * 2048]);
    float Bf[16];
#pragma unroll
    for (int q = 0; q < 4; ++q)
      *reinterpret_cast<float4*>(&Bf[q * 4]) =
          *reinterpret_cast<const float4*>(xb + (size_t)t * 96 + q * 4);
    float dlu = dl * ul;
    sd += dl;
#pragma unroll
    for (int n = 0; n < 16; ++n)
      h[n] = __expf(dl * Ac[n]) * h[n] + dlu * Bf[n];
  }
  sdl[((size_t)b * NC + c) * 2048 + d] = sd;
  float* hs = HS + (((size_t)b * NC + c) * 2048 + d) * 16;
#pragma unroll
  for (int q = 0; q < 4; ++q)
    *reinterpret_cast<float4*>(hs + q * 4) =
        make_float4(h[q * 4], h[q * 4 + 1], h[q * 4 + 2], h[q * 4 + 3]);
}

// pass2: in-place combine over chunks, fully unrolled
__global__ __launch_bounds__(256)
void scan_pass2(const float* __restrict__ sdl, const float* __restrict__ A_log,
                float* __restrict__ HS)
{
  const int gid = blockIdx.x * 256 + threadIdx.x;  // 0..65535
  const int b = gid >> 15, rest = gid & 32767;     // rest = d*16+n
  const int d = rest >> 4;
  const float Ac = -__expf(A_log[rest]);
  float P[NC], S[NC];
#pragma unroll
  for (int c = 0; c < NC; ++c)
    P[c] = sdl[(((size_t)b * NC + c) << 11) + d];
#pragma unroll
  for (int c = 0; c < NC; ++c)
    S[c] = HS[(((size_t)b * NC + c) << 15) + rest];
#pragma unroll
  for (int c = 0; c < NC; ++c)
    P[c] = __expf(P[c] * Ac);
  float h = 0.f;
#pragma unroll
  for (int c = 0; c < NC; ++c) {
    HS[(((size_t)b * NC + c) << 15) + rest] = h;
    h = P[c] * h + S[c];
  }
}

// pass3: scan from HS, local n-reduce, z = y * silu_res (rb already silu'd bf16)
__global__ __launch_bounds__(256, 4)
void scan_pass3(const unsigned short* __restrict__ deltab, const unsigned short* __restrict__ ub,
                const float* __restrict__ xp, const float* __restrict__ A_log,
                const float* __restrict__ HS, const unsigned short* __restrict__ rb,
                short* __restrict__ zb)
{
  const int d = blockIdx.y * 256 + threadIdx.x;
  const int c = blockIdx.x, b = blockIdx.z;
  const int t0 = (b << 10) + c * LC;
  float Ac[16];
#pragma unroll
  for (int q = 0; q < 4; ++q) {
    float4 a = *reinterpret_cast<const float4*>(A_log + (size_t)d * 16 + q * 4);
    Ac[q * 4 + 0] = -__expf(a.x); Ac[q * 4 + 1] = -__expf(a.y);
    Ac[q * 4 + 2] = -__expf(a.z); Ac[q * 4 + 3] = -__expf(a.w);
  }
  float h[16];
  const float* hs = HS + (((size_t)b * NC + c) * 2048 + d) * 16;
#pragma unroll
  for (int q = 0; q < 4; ++q) {
    float4 v = *reinterpret_cast<const float4*>(hs + q * 4);
    h[q * 4 + 0] = v.x; h[q * 4 + 1] = v.y; h[q * 4 + 2] = v.z; h[q * 4 + 3] = v.w;
  }
  const unsigned short* dp = deltab + (size_t)t0 * 2048 + d;
  const unsigned short* up = ub + (size_t)t0 * 2048 + d;
  const float* xb = xp + (size_t)t0 * 96 + DT_RANK;
  const float* xc = xp + (size_t)t0 * 96 + DT_RANK + N_ST;
  const unsigned short* rp = rb + (size_t)t0 * 2048 + d;
  short* zp = zb + (size_t)t0 * 2048 + d;
#pragma unroll 4
  for (int t = 0; t < LC; ++t) {
    float dl = b2f(dp[(size_t)t * 2048]);
    float ul = b2f(up[(size_t)t * 2048]);
    float rv = b2f(rp[(size_t)t * 2048]);   // silu(res) already applied
    float Bf[16], Cf[16];
#pragma unroll
    for (int q = 0; q < 4; ++q) {
      *reinterpret_cast<float4*>(&Bf[q * 4]) =
          *reinterpret_cast<const float4*>(xb + (size_t)t * 96 + q * 4);
      *reinterpret_cast<float4*>(&Cf[q * 4]) =
          *reinterpret_cast<const float4*>(xc + (size_t)t * 96 + q * 4);
    }
    float dlu = dl * ul;
    float p0 = 0.f, p1 = 0.f, p2 = 0.f, p3 = 0.f;
#pragma unroll
    for (int n = 0; n < 16; ++n) {
      h[n] = __expf(dl * Ac[n]) * h[n] + dlu * Bf[n];
      float t2 = h[n] * Cf[n];
      if ((n & 3) == 0) p0 += t2;
      else if ((n & 3) == 1) p1 += t2;
      else if ((n & 3) == 2) p2 += t2;
      else p3 += t2;
    }
    float p = (p0 + p1) + (p2 + p3);
    zp[(size_t)t * 2048] = f2b(p * rv);
  }
}

extern "C" void kernel_launch(void* const* d_in, const int* in_sizes, int n_in,
                              void* d_out, int out_size, void* d_ws, size_t ws_size,
                              hipStream_t stream)
{
  const float* x      = (const float*)d_in[0];
  const float* A_log  = (const float*)d_in[1];
  const float* W_in   = (const float*)d_in[2];
  const float* b_in   = (const float*)d_in[3];
  const float* conv_w = (const float*)d_in[4];
  const float* conv_b = (const float*)d_in[5];
  const float* W_x    = (const float*)d_in[6];
  const float* W_dt   = (const float*)d_in[7];
  const float* b_dt   = (const float*)d_in[8];
  const float* W_out  = (const float*)d_in[9];
  const float* b_out  = (const float*)d_in[10];
  float* out = (float*)d_out;

  // workspace layout (~90 MB)
  char* p = (char*)d_ws;
  short* upb    = (short*)p; p += (size_t)NTOK * 2048 * 2;          // 8MB u_pre bf16 (boundary rows)
  short* rb     = (short*)p; p += (size_t)NTOK * 2048 * 2;          // 8MB silu(res) bf16
  short* ub     = (short*)p; p += (size_t)NTOK * 2048 * 2;          // 8MB
  float* xp     = (float*)p; p += (size_t)NTOK * 96 * 4;            // .75MB dt|B|C fp32
  short* dtb    = (short*)p; p += (size_t)NTOK * 64 * 2;            // .25MB
  short* deltab = (short*)p; p += (size_t)NTOK * 2048 * 2;          // 8MB bf16
  short* zb     = (short*)p; p += (size_t)NTOK * 2048 * 2;          // 8MB
  short* xb     = (short*)p; p += (size_t)NTOK * 1024 * 2;          // 4MB
  short* Wib    = (short*)p; p += (size_t)4096 * 1024 * 2;          // 8MB
  short* Wxb    = (short*)p; p += (size_t)128 * 2048 * 2;           // .5MB (96 rows + pad)
  short* Wdtb   = (short*)p; p += (size_t)2048 * 64 * 2;            // .25MB
  short* Wob    = (short*)p; p += (size_t)1024 * 2048 * 2;          // 4MB
  char*  scr    = p;         p += (size_t)16 * 1024 * 1024;         // 16MB shared scratch
  float* xppart = (float*)scr;  // 16 x 2048 x 96 fp32 = 12.6MB (GEMM2..combine16)
  short* opart  = (short*)scr;  // 4 x 2048 x 1024 bf16 = 16MB (GEMM4..combine4)
  float* sdl    = (float*)p; p += (size_t)BSZ * NC * 2048 * 4;      // .5MB
  float* HS     = (float*)p; p += (size_t)BSZ * NC * 2048 * 16 * 4; // 8MB

  // all pre-casts/transposes in one dispatch
  prep_kernel<<<dim3(PB_CAST + PB_WIN + PB_WX + PB_WDT + PB_WOUT), 256, 0, stream>>>(
      x, W_in, W_x, W_dt, W_out, xb, Wib, Wxb, Wdtb, Wob);

  // GEMM1: upb(boundary u_pre) | ub(conv+silu rows 2..127) | rb(silu(res))
  gemm_kernel<0, 0, 1, 0, 0><<<dim3(32, 16, 1), 256, 0, stream>>>(
      xb, Wib, b_in, nullptr, upb, rb, conv_w, conv_b, ub,
      NTOK, 4096, 1024, 1024, 1024, 0, 1024);
  // xp partials = u @ W_x (split-K 16, no atomics); prologue fixes boundary ub
  gemm_kernel<0, 1, 0, 0, 1><<<dim3(1, 16, 16), 256, 0, stream>>>(
      ub, Wxb, nullptr, xppart, upb, nullptr, conv_w, conv_b, ub,
      NTOK, 96, 2048, 2048, 2048, 96, 128);
  // xp = sum(partials); dtb = bf16(dt cols)
  combine16_kernel<<<dim3(192), 256, 0, stream>>>(xppart, xp, dtb);
  // deltab = bf16(softplus(dt @ W_dt + b_dt))
  gemm_kernel<1, 0, 0, 1, 0><<<dim3(16, 16, 1), 256, 0, stream>>>(
      dtb, Wdtb, b_dt, nullptr, deltab, nullptr, nullptr, nullptr, nullptr,
      NTOK, 2048, 64, 64, 64, 2048, 64);
  // chunked selective scan -> zb (bf16, zmul fused)
  scan_pass1<<<dim3(NC, 8, BSZ), 256, 0, stream>>>(
      (const unsigned short*)deltab, (const unsigned short*)ub, xp, A_log, sdl, HS);
  scan_pass2<<<dim3(256), 256, 0, stream>>>(sdl, A_log, HS);
  scan_pass3<<<dim3(NC, 8, BSZ), 256, 0, stream>>>(
      (const unsigned short*)deltab, (const unsigned short*)ub, xp, A_log, HS,
      (const unsigned short*)rb, zb);
  // opart(bf16) = z @ W_out partials (split-K 4, no atomics)
  gemm_kernel<0, 2, 0, 0, 0><<<dim3(8, 16, 4), 256, 0, stream>>>(
      zb, Wob, nullptr, (float*)opart, nullptr, nullptr, nullptr, nullptr, nullptr,
      NTOK, 1024, 2048, 2048, 2048, 1024, 512);
  // out = sum(partials) + b_out
  combine4_kernel<<<dim3(2048), 256, 0, stream>>>(
      (const unsigned short*)opart, b_out, out);
}

// Round 16
// 141.421 us; speedup vs baseline: 1.0190x; 1.0190x over previous
//
#include <hip/hip_runtime.h>

#define D_MODEL 1024
#define D_INNER 2048
#define N_ST    16
#define DT_RANK 64
#define BSZ     2
#define SEQL    1024
#define NTOK    (BSZ*SEQL)   // 2048
#define NC      32           // scan chunks
#define LC      (SEQL/NC)    // 32 steps per chunk

typedef __attribute__((ext_vector_type(4))) float f32x4;
typedef __attribute__((ext_vector_type(8))) short bf16x8;

__device__ __forceinline__ short f2b(float f) {
  unsigned u = __builtin_bit_cast(unsigned, f);
  u += 0x7fffu + ((u >> 16) & 1u);           // round-to-nearest-even
  return (short)(u >> 16);
}

__device__ __forceinline__ float b2f(unsigned short s) {
  return __builtin_bit_cast(float, (unsigned)s << 16);
}

__device__ __forceinline__ void gload16(const void* g, void* l) {
  __builtin_amdgcn_global_load_lds(
      (const __attribute__((address_space(1))) void*)g,
      (__attribute__((address_space(3))) void*)l, 16, 0, 0);
}

// C[M,N] = epi(A[M,K] @ B[N,K]^T + bias); A,B bf16 (B pre-transposed [N][K]).
// 128x128 tile, BK=32, 48 KB LDS (3-deep rotation x 8KB x {A,B}).
// ONE barrier per K-step: STAGE(t+1 -> buf[(t+1)%3]) -> vmcnt(4) -> barrier ->
// MFMA(buf[t%3]). Swizzle: granule g' = g ^ ((row>>1)&3) on both sides.
// ALL kernels: XCD-chunked bijective block remap (grid total % 8 == 0) so
// blocks sharing A-row/B-col panels co-locate on one XCD's L2 (T1).
// PARTIAL: 1 = fp32 partials at z*M*ldc; 2 = bf16 partials.
// RESSPLIT (GEMM1): cols<2048 -> u_pre: boundary rows to upb, fused conv+silu
//   rows 2..127 to ubuf (via 32KB LDS tile); cols>=2048 -> silu bf16 to resb.
// OUTB16: store epi result bf16 to upb at ldc stride.
// FIXUP (GEMM2): prologue finishes conv+silu for this block's 2 boundary
//   tokens x its 128-d slice (A region), writing ubuf before staging.
template<int SOFTPLUS, int PARTIAL, int RESSPLIT, int OUTB16, int FIXUP>
__global__ __launch_bounds__(256)
void gemm_kernel(const short* __restrict__ A, const short* __restrict__ Bm,
                 const float* __restrict__ bias, float* __restrict__ C,
                 short* __restrict__ upb, short* __restrict__ resb,
                 const float* __restrict__ cw, const float* __restrict__ cb,
                 short* __restrict__ ubuf,
                 int M, int N, int K, int lda, int ldb, int ldc, int kChunk)
{
  __shared__ short lds[24576];   // 48 KB: A bufs 0/4096/8192; B bufs +12288
  const int tid  = threadIdx.x;
  const int lane = tid & 63;
  const int wave = tid >> 6;
  const int wr = wave >> 1, wc = wave & 1;
  const int lr = lane & 15, lg = lane >> 4;

  // XCD-chunked bijective remap (total blocks % 8 == 0 for all callers)
  int bx, by, bz;
  {
    const int gx = gridDim.x, gy = gridDim.y;
    const int total = gx * gy * gridDim.z;
    const int lin = (blockIdx.z * gy + blockIdx.y) * gx + blockIdx.x;
    const int q = total >> 3;
    int lb = (lin & 7) * q + (lin >> 3);
    if (RESSPLIT) {            // GEMM1: y-major within XCD (proven layout)
      lb = (lin & 7) * 64 + (lin >> 3);
      bx = lb >> 4; by = lb & 15; bz = 0;
    } else {
      bx = lb % gx; lb /= gx;
      by = lb % gy; bz = lb / gy;
    }
  }
  const int m0 = by * 128;
  const int n0 = bx * 128;
  const int kStart = bz * kChunk;
  int kEnd = kStart + kChunk; if (kEnd > K) kEnd = K;
  const int nt = (kEnd - kStart) >> 5;   // BK=32 steps

  if (FIXUP) {
    // finish conv+silu for boundary tokens {m0, m0+1} x d-slice [kStart,+128)
    const int tt = m0 + (tid >> 7);
    const int dd = kStart + (tid & 127);
    const int l  = tt & (SEQL - 1);
    float u2 = b2f((unsigned short)upb[(size_t)tt * 2048 + dd]);
    float u1 = (l >= 1) ? b2f((unsigned short)upb[(size_t)(tt - 1) * 2048 + dd]) : 0.f;
    float u0 = (l >= 2) ? b2f((unsigned short)upb[(size_t)(tt - 2) * 2048 + dd]) : 0.f;
    float r = cb[dd] + cw[dd * 3] * u0 + cw[dd * 3 + 1] * u1 + cw[dd * 3 + 2] * u2;
    ubuf[(size_t)tt * 2048 + dd] = f2b(r / (1.f + __expf(-r)));
    asm volatile("s_waitcnt vmcnt(0)" ::: "memory");  // stores retired to L2
    __syncthreads();                                  // before any gload16 reads them
  }

  // staging: wave covers 32 rows; one gload16 covers 16 rows x 32 k (1 KB).
  const int srow = lane >> 2;                          // 0..15
  const int sgran = (lane & 3) ^ ((lane >> 3) & 3);    // (lane&3) ^ ((srow>>1)&3)
  const short* aS = A + (size_t)(m0 + wave * 32 + srow) * lda + sgran * 8 + kStart;
  const short* bS = Bm + (size_t)(n0 + wave * 32 + srow) * ldb + sgran * 8 + kStart;
  const int ldsOff = wave * 1024;                      // wave's 32x32 region (shorts)

#define STAGE(buf, koff)                                                        \
  {                                                                             \
    _Pragma("unroll")                                                           \
    for (int i_ = 0; i_ < 2; ++i_) {                                            \
      gload16(aS + (size_t)(i_ * 16) * lda + (koff),                            \
              &lds[(buf) * 4096 + ldsOff + i_ * 512]);                          \
      gload16(bS + (size_t)(i_ * 16) * ldb + (koff),                            \
              &lds[12288 + (buf) * 4096 + ldsOff + i_ * 512]);                  \
    }                                                                           \
  }

  f32x4 acc[4][4];
#pragma unroll
  for (int i = 0; i < 4; ++i)
#pragma unroll
    for (int j = 0; j < 4; ++j) acc[i][j] = (f32x4){0.f, 0.f, 0.f, 0.f};

  STAGE(0, 0);

  int cur = 0, nxt = 1;
  for (int t = 0; t < nt; ++t) {
    if (t + 1 < nt) {
      STAGE(nxt, (t + 1) * 32);
      asm volatile("s_waitcnt vmcnt(4)" ::: "memory");  // tile-t staged; t+1 in flight
    } else {
      asm volatile("s_waitcnt vmcnt(0)" ::: "memory");
    }
    __builtin_amdgcn_s_barrier();   // buf[cur] visible to all waves

    bf16x8 aF[4], bF[4];
#pragma unroll
    for (int mi = 0; mi < 4; ++mi) {
      const int row = wr * 64 + mi * 16 + lr;
      aF[mi] = *reinterpret_cast<const bf16x8*>(
          &lds[cur * 4096 + row * 32 + ((lg ^ ((row >> 1) & 3)) << 3)]);
    }
#pragma unroll
    for (int ni = 0; ni < 4; ++ni) {
      const int row = wc * 64 + ni * 16 + lr;
      bF[ni] = *reinterpret_cast<const bf16x8*>(
          &lds[12288 + cur * 4096 + row * 32 + ((lg ^ ((row >> 1) & 3)) << 3)]);
    }
#pragma unroll
    for (int mi = 0; mi < 4; ++mi)
#pragma unroll
      for (int ni = 0; ni < 4; ++ni)
        acc[mi][ni] = __builtin_amdgcn_mfma_f32_16x16x32_bf16(
            aF[mi], bF[ni], acc[mi][ni], 0, 0, 0);

    cur = nxt; nxt = (nxt == 2) ? 0 : nxt + 1;   // no post-MFMA barrier (3-deep)
  }
#undef STAGE
  __syncthreads();   // all waves done reading LDS before epilogue reuse

  // epilogue: C/D layout col=lane&15, row=(lane>>4)*4+reg
  if (RESSPLIT) {
    if (n0 < 2048) {
      // u_pre tile -> LDS (first 32KB = 128x128 bf16); boundary rows -> upb
      short (*sU)[128] = reinterpret_cast<short (*)[128]>(&lds[0]);
#pragma unroll
      for (int mi = 0; mi < 4; ++mi) {
#pragma unroll
        for (int ni = 0; ni < 4; ++ni) {
          const int cl = wc * 64 + ni * 16 + lr;
          const float bv = bias[n0 + cl];
#pragma unroll
          for (int j = 0; j < 4; ++j) {
            const int rl = wr * 64 + mi * 16 + lg * 4 + j;
            const short s = f2b(acc[mi][ni][j] + bv);
            sU[rl][cl] = s;
            if (rl < 2 || rl >= 126)
              upb[(size_t)(m0 + rl) * 2048 + (n0 + cl)] = s;
          }
        }
      }
      __syncthreads();
      // fused causal conv(K=3) + bias + silu for rows 2..127
#pragma unroll
      for (int ni = 0; ni < 4; ++ni) {
        const int cl = wc * 64 + ni * 16 + lr;
        const int col = n0 + cl;
        const float w0 = cw[col * 3], w1 = cw[col * 3 + 1], w2 = cw[col * 3 + 2];
        const float cbv = cb[col];
#pragma unroll
        for (int mi = 0; mi < 4; ++mi) {
#pragma unroll
          for (int j = 0; j < 4; ++j) {
            const int rl = wr * 64 + mi * 16 + lg * 4 + j;
            if (rl >= 2) {
              float r = cbv + w0 * b2f((unsigned short)sU[rl - 2][cl])
                            + w1 * b2f((unsigned short)sU[rl - 1][cl])
                            + w2 * b2f((unsigned short)sU[rl][cl]);
              ubuf[(size_t)(m0 + rl) * 2048 + col] = f2b(r / (1.f + __expf(-r)));
            }
          }
        }
      }
    } else {
#pragma unroll
      for (int mi = 0; mi < 4; ++mi) {
        const int row = m0 + wr * 64 + mi * 16 + lg * 4;
#pragma unroll
        for (int ni = 0; ni < 4; ++ni) {
          const int col = n0 + wc * 64 + ni * 16 + lr;
          const float bv = bias[col];
#pragma unroll
          for (int j = 0; j < 4; ++j) {
            float v = acc[mi][ni][j] + bv;
            resb[(size_t)(row + j) * 2048 + (col - 2048)] =
                f2b(v / (1.f + __expf(-v)));
          }
        }
      }
    }
    return;
  }

#pragma unroll
  for (int mi = 0; mi < 4; ++mi) {
    const int row = m0 + wr * 64 + mi * 16 + lg * 4;
#pragma unroll
    for (int ni = 0; ni < 4; ++ni) {
      const int col = n0 + wc * 64 + ni * 16 + lr;
      if (OUTB16) {
        const float bv = bias[col];
#pragma unroll
        for (int j = 0; j < 4; ++j) {
          float v = acc[mi][ni][j] + bv;
          if (SOFTPLUS) v = fmaxf(v, 0.f) + log1pf(__expf(-fabsf(v)));
          upb[(size_t)(row + j) * ldc + col] = f2b(v);
        }
      } else if (PARTIAL == 2) {
        short* Cs = (short*)C + (size_t)bz * M * ldc;
#pragma unroll
        for (int j = 0; j < 4; ++j)
          Cs[(size_t)(row + j) * ldc + col] = f2b(acc[mi][ni][j]);
      } else if (col < N) {
        float* Cp = PARTIAL ? C + (size_t)bz * M * ldc : C;
        float bv = (bias != nullptr && bz == 0) ? bias[col] : 0.f;
#pragma unroll
        for (int j = 0; j < 4; ++j) {
          float v = acc[mi][ni][j] + bv;
          if (SOFTPLUS) v = fmaxf(v, 0.f) + log1pf(__expf(-fabsf(v)));
          Cp[(size_t)(row + j) * ldc + col] = v;
        }
      }
    }
  }
}

// ---- fused prep: castA(x) + transpose-cast of all 4 weights, one dispatch ----
__device__ __forceinline__ void trans_body(const float* __restrict__ in,
                                           short* __restrict__ out,
                                           int R, int C, int bx, int by,
                                           short (*t)[33], int tidx)
{
  const int c0 = bx * 32, r0 = by * 32;
  const int cc = tidx & 31, rr = tidx >> 5;  // rr 0..7
#pragma unroll
  for (int i = 0; i < 4; ++i)
    t[rr + i * 8][cc] = f2b(in[(size_t)(r0 + rr + i * 8) * C + c0 + cc]);
  __syncthreads();
#pragma unroll
  for (int i = 0; i < 4; ++i)
    out[(size_t)(c0 + rr + i * 8) * R + r0 + cc] = t[cc][rr + i * 8];
}

#define PB_CAST  2048
#define PB_WIN   4096
#define PB_WX    192
#define PB_WDT   128
#define PB_WOUT  2048

__global__ __launch_bounds__(256)
void prep_kernel(const float* __restrict__ x,    const float* __restrict__ W_in,
                 const float* __restrict__ W_x,  const float* __restrict__ W_dt,
                 const float* __restrict__ W_out,
                 short* __restrict__ xb,  short* __restrict__ Wib,
                 short* __restrict__ Wxb, short* __restrict__ Wdtb,
                 short* __restrict__ Wob)
{
  __shared__ short t[32][33];
  const int bid = blockIdx.x, tidx = threadIdx.x;
  if (bid < PB_CAST) {
    const int i = bid * 256 + tidx;
    float4 v = *reinterpret_cast<const float4*>(x + (size_t)i * 4);
    *reinterpret_cast<short4*>(xb + (size_t)i * 4) =
        make_short4(f2b(v.x), f2b(v.y), f2b(v.z), f2b(v.w));
  } else if (bid < PB_CAST + PB_WIN) {
    const int b = bid - PB_CAST;
    trans_body(W_in, Wib, 1024, 4096, b % 128, b / 128, t, tidx);
  } else if (bid < PB_CAST + PB_WIN + PB_WX) {
    const int b = bid - PB_CAST - PB_WIN;
    trans_body(W_x, Wxb, 2048, 96, b % 3, b / 3, t, tidx);
  } else if (bid < PB_CAST + PB_WIN + PB_WX + PB_WDT) {
    const int b = bid - PB_CAST - PB_WIN - PB_WX;
    trans_body(W_dt, Wdtb, 64, 2048, b % 64, b / 64, t, tidx);
  } else {
    const int b = bid - PB_CAST - PB_WIN - PB_WX - PB_WDT;
    trans_body(W_out, Wob, 2048, 1024, b % 32, b / 32, t, tidx);
  }
}

// combine 16 split-K partials of GEMM2 -> xp fp32 [2048][96]; dt cols -> dtb bf16
__global__ __launch_bounds__(256)
void combine16_kernel(const float* __restrict__ part, float* __restrict__ xp,
                      short* __restrict__ dtb)
{
  const int gid = blockIdx.x * 256 + threadIdx.x;   // 0 .. 2048*24-1
  const int r = gid / 24, q = gid - r * 24;
  float4 s = make_float4(0.f, 0.f, 0.f, 0.f);
#pragma unroll
  for (int c = 0; c < 16; ++c) {
    const float4 v = *reinterpret_cast<const float4*>(
        part + (size_t)c * 2048 * 96 + (size_t)r * 96 + q * 4);
    s.x += v.x; s.y += v.y; s.z += v.z; s.w += v.w;
  }
  *reinterpret_cast<float4*>(xp + (size_t)r * 96 + q * 4) = s;
  if (q < 16)
    *reinterpret_cast<short4*>(dtb + (size_t)r * 64 + q * 4) =
        make_short4(f2b(s.x), f2b(s.y), f2b(s.z), f2b(s.w));
}

// combine 4 bf16 split-K partials of GEMM4 + bias -> out fp32 [2048][1024]
__global__ __launch_bounds__(256)
void combine4_kernel(const unsigned short* __restrict__ part,
                     const float* __restrict__ bias, float* __restrict__ out)
{
  const int gid = blockIdx.x * 256 + threadIdx.x;   // over 2048*256 float4s
  const int r = gid >> 8, c4 = gid & 255;
  const float4 bv = *reinterpret_cast<const float4*>(bias + c4 * 4);
  float4 s = bv;
#pragma unroll
  for (int z = 0; z < 4; ++z) {
    const ushort4 v = *reinterpret_cast<const ushort4*>(
        part + (size_t)z * 2048 * 1024 + (size_t)r * 1024 + c4 * 4);
    s.x += b2f(v.x); s.y += b2f(v.y); s.z += b2f(v.z); s.w += b2f(v.w);
  }
  *reinterpret_cast<float4*>(out + (size_t)r * 1024 + c4 * 4) = s;
}

// ---- chunked selective scan: thread owns (b, chunk, d) with all 16 n ----
__global__ __launch_bounds__(256, 4)
void scan_pass1(const unsigned short* __restrict__ deltab, const unsigned short* __restrict__ ub,
                const float* __restrict__ xp, const float* __restrict__ A_log,
                float* __restrict__ sdl, float* __restrict__ HS)
{
  const int d = blockIdx.y * 256 + threadIdx.x;
  const int c = blockIdx.x, b = blockIdx.z;
  const int t0 = (b << 10) + c * LC;
  float Ac[16];
#pragma unroll
  for (int q = 0; q < 4; ++q) {
    float4 a = *reinterpret_cast<const float4*>(A_log + (size_t)d * 16 + q * 4);
    Ac[q * 4 + 0] = -__expf(a.x); Ac[q * 4 + 1] = -__expf(a.y);
    Ac[q * 4 + 2] = -__expf(a.z); Ac[q * 4 + 3] = -__expf(a.w);
  }
  float h[16];
#pragma unroll
  for (int n = 0; n < 16; ++n) h[n] = 0.f;
  float sd = 0.f;
  const unsigned short* dp = deltab + (size_t)t0 * 2048 + d;
  const unsigned short* up = ub + (size_t)t0 * 2048 + d;
  const float* xb = xp + (size_t)t0 * 96 + DT_RANK;
#pragma unroll 4
  for (int t = 0; t < LC; ++t) {
    float dl = b2f(dp[(size_t)t * 2048]);
    float ul = b2f(up[(size_t)t * 2048]);
    float Bf[16];
#pragma unroll
    for (int q = 0; q < 4; ++q)
      *reinterpret_cast<float4*>(&Bf[q * 4]) =
          *reinterpret_cast<const float4*>(xb + (size_t)t * 96 + q * 4);
    float dlu = dl * ul;
    sd += dl;
#pragma unroll
    for (int n = 0; n < 16; ++n)
      h[n] = __expf(dl * Ac[n]) * h[n] + dlu * Bf[n];
  }
  sdl[((size_t)b * NC + c) * 2048 + d] = sd;
  float* hs = HS + (((size_t)b * NC + c) * 2048 + d) * 16;
#pragma unroll
  for (int q = 0; q < 4; ++q)
    *reinterpret_cast<float4*>(hs + q * 4) =
        make_float4(h[q * 4], h[q * 4 + 1], h[q * 4 + 2], h[q * 4 + 3]);
}

// pass2: in-place combine over chunks, fully unrolled
__global__ __launch_bounds__(256)
void scan_pass2(const float* __restrict__ sdl, const float* __restrict__ A_log,
                float* __restrict__ HS)
{
  const int gid = blockIdx.x * 256 + threadIdx.x;  // 0..65535
  const int b = gid >> 15, rest = gid & 32767;     // rest = d*16+n
  const int d = rest >> 4;
  const float Ac = -__expf(A_log[rest]);
  float P[NC], S[NC];
#pragma unroll
  for (int c = 0; c < NC; ++c)
    P[c] = sdl[(((size_t)b * NC + c) << 11) + d];
#pragma unroll
  for (int c = 0; c < NC; ++c)
    S[c] = HS[(((size_t)b * NC + c) << 15) + rest];
#pragma unroll
  for (int c = 0; c < NC; ++c)
    P[c] = __expf(P[c] * Ac);
  float h = 0.f;
#pragma unroll
  for (int c = 0; c < NC; ++c) {
    HS[(((size_t)b * NC + c) << 15) + rest] = h;
    h = P[c] * h + S[c];
  }
}

// pass3: scan from HS, local n-reduce, z = y * silu_res (rb already silu'd bf16)
__global__ __launch_bounds__(256, 4)
void scan_pass3(const unsigned short* __restrict__ deltab, const unsigned short* __restrict__ ub,
                const float* __restrict__ xp, const float* __restrict__ A_log,
                const float* __restrict__ HS, const unsigned short* __restrict__ rb,
                short* __restrict__ zb)
{
  const int d = blockIdx.y * 256 + threadIdx.x;
  const int c = blockIdx.x, b = blockIdx.z;
  const int t0 = (b << 10) + c * LC;
  float Ac[16];
#pragma unroll
  for (int q = 0; q < 4; ++q) {
    float4 a = *reinterpret_cast<const float4*>(A_log + (size_t)d * 16 + q * 4);
    Ac[q * 4 + 0] = -__expf(a.x); Ac[q * 4 + 1] = -__expf(a.y);
    Ac[q * 4 + 2] = -__expf(a.z); Ac[q * 4 + 3] = -__expf(a.w);
  }
  float h[16];
  const float* hs = HS + (((size_t)b * NC + c) * 2048 + d) * 16;
#pragma unroll
  for (int q = 0; q < 4; ++q) {
    float4 v = *reinterpret_cast<const float4*>(hs + q * 4);
    h[q * 4 + 0] = v.x; h[q * 4 + 1] = v.y; h[q * 4 + 2] = v.z; h[q * 4 + 3] = v.w;
  }
  const unsigned short* dp = deltab + (size_t)t0 * 2048 + d;
  const unsigned short* up = ub + (size_t)t0 * 2048 + d;
  const float* xb = xp + (size_t)t0 * 96 + DT_RANK;
  const float* xc = xp + (size_t)t0 * 96 + DT_RANK + N_ST;
  const unsigned short* rp = rb + (size_t)t0 * 2048 + d;
  short* zp = zb + (size_t)t0 * 2048 + d;
#pragma unroll 4
  for (int t = 0; t < LC; ++t) {
    float dl = b2f(dp[(size_t)t * 2048]);
    float ul = b2f(up[(size_t)t * 2048]);
    float rv = b2f(rp[(size_t)t * 2048]);   // silu(res) already applied
    float Bf[16], Cf[16];
#pragma unroll
    for (int q = 0; q < 4; ++q) {
      *reinterpret_cast<float4*>(&Bf[q * 4]) =
          *reinterpret_cast<const float4*>(xb + (size_t)t * 96 + q * 4);
      *reinterpret_cast<float4*>(&Cf[q * 4]) =
          *reinterpret_cast<const float4*>(xc + (size_t)t * 96 + q * 4);
    }
    float dlu = dl * ul;
    float p0 = 0.f, p1 = 0.f, p2 = 0.f, p3 = 0.f;
#pragma unroll
    for (int n = 0; n < 16; ++n) {
      h[n] = __expf(dl * Ac[n]) * h[n] + dlu * Bf[n];
      float t2 = h[n] * Cf[n];
      if ((n & 3) == 0) p0 += t2;
      else if ((n & 3) == 1) p1 += t2;
      else if ((n & 3) == 2) p2 += t2;
      else p3 += t2;
    }
    float p = (p0 + p1) + (p2 + p3);
    zp[(size_t)t * 2048] = f2b(p * rv);
  }
}

extern "C" void kernel_launch(void* const* d_in, const int* in_sizes, int n_in,
                              void* d_out, int out_size, void* d_ws, size_t ws_size,
                              hipStream_t stream)
{
  const float* x      = (const float*)d_in[0];
  const float* A_log  = (const float*)d_in[1];
  const float* W_in   = (const float*)d_in[2];
  const float* b_in   = (const float*)d_in[3];
  const float* conv_w = (const float*)d_in[4];
  const float* conv_b = (const float*)d_in[5];
  const float* W_x    = (const float*)d_in[6];
  const float* W_dt   = (const float*)d_in[7];
  const float* b_dt   = (const float*)d_in[8];
  const float* W_out  = (const float*)d_in[9];
  const float* b_out  = (const float*)d_in[10];
  float* out = (float*)d_out;

  // workspace layout (~90 MB)
  char* p = (char*)d_ws;
  short* upb    = (short*)p; p += (size_t)NTOK * 2048 * 2;          // 8MB u_pre bf16 (boundary rows)
  short* rb     = (short*)p; p += (size_t)NTOK * 2048 * 2;          // 8MB silu(res) bf16
  short* ub     = (short*)p; p += (size_t)NTOK * 2048 * 2;          // 8MB
  float* xp     = (float*)p; p += (size_t)NTOK * 96 * 4;            // .75MB dt|B|C fp32
  short* dtb    = (short*)p; p += (size_t)NTOK * 64 * 2;            // .25MB
  short* deltab = (short*)p; p += (size_t)NTOK * 2048 * 2;          // 8MB bf16
  short* zb     = (short*)p; p += (size_t)NTOK * 2048 * 2;          // 8MB
  short* xb     = (short*)p; p += (size_t)NTOK * 1024 * 2;          // 4MB
  short* Wib    = (short*)p; p += (size_t)4096 * 1024 * 2;          // 8MB
  short* Wxb    = (short*)p; p += (size_t)128 * 2048 * 2;           // .5MB (96 rows + pad)
  short* Wdtb   = (short*)p; p += (size_t)2048 * 64 * 2;            // .25MB
  short* Wob    = (short*)p; p += (size_t)1024 * 2048 * 2;          // 4MB
  char*  scr    = p;         p += (size_t)16 * 1024 * 1024;         // 16MB shared scratch
  float* xppart = (float*)scr;  // 16 x 2048 x 96 fp32 = 12.6MB (GEMM2..combine16)
  short* opart  = (short*)scr;  // 4 x 2048 x 1024 bf16 = 16MB (GEMM4..combine4)
  float* sdl    = (float*)p; p += (size_t)BSZ * NC * 2048 * 4;      // .5MB
  float* HS     = (float*)p; p += (size_t)BSZ * NC * 2048 * 16 * 4; // 8MB

  // all pre-casts/transposes in one dispatch
  prep_kernel<<<dim3(PB_CAST + PB_WIN + PB_WX + PB_WDT + PB_WOUT), 256, 0, stream>>>(
      x, W_in, W_x, W_dt, W_out, xb, Wib, Wxb, Wdtb, Wob);

  // GEMM1: upb(boundary u_pre) | ub(conv+silu rows 2..127) | rb(silu(res))
  gemm_kernel<0, 0, 1, 0, 0><<<dim3(32, 16, 1), 256, 0, stream>>>(
      xb, Wib, b_in, nullptr, upb, rb, conv_w, conv_b, ub,
      NTOK, 4096, 1024, 1024, 1024, 0, 1024);
  // xp partials = u @ W_x (split-K 16, no atomics); prologue fixes boundary ub
  gemm_kernel<0, 1, 0, 0, 1><<<dim3(1, 16, 16), 256, 0, stream>>>(
      ub, Wxb, nullptr, xppart, upb, nullptr, conv_w, conv_b, ub,
      NTOK, 96, 2048, 2048, 2048, 96, 128);
  // xp = sum(partials); dtb = bf16(dt cols)
  combine16_kernel<<<dim3(192), 256, 0, stream>>>(xppart, xp, dtb);
  // deltab = bf16(softplus(dt @ W_dt + b_dt))
  gemm_kernel<1, 0, 0, 1, 0><<<dim3(16, 16, 1), 256, 0, stream>>>(
      dtb, Wdtb, b_dt, nullptr, deltab, nullptr, nullptr, nullptr, nullptr,
      NTOK, 2048, 64, 64, 64, 2048, 64);
  // chunked selective scan -> zb (bf16, zmul fused)
  scan_pass1<<<dim3(NC, 8, BSZ), 256, 0, stream>>>(
      (const unsigned short*)deltab, (const unsigned short*)ub, xp, A_log, sdl, HS);
  scan_pass2<<<dim3(256), 256, 0, stream>>>(sdl, A_log, HS);
  scan_pass3<<<dim3(NC, 8, BSZ), 256, 0, stream>>>(
      (const unsigned short*)deltab, (const unsigned short*)ub, xp, A_log, HS,
      (const unsigned short*)rb, zb);
  // opart(bf16) = z @ W_out partials (split-K 4, no atomics)
  gemm_kernel<0, 2, 0, 0, 0><<<dim3(8, 16, 4), 256, 0, stream>>>(
      zb, Wob, nullptr, (float*)opart, nullptr, nullptr, nullptr, nullptr, nullptr,
      NTOK, 1024, 2048, 2048, 2048, 1024, 512);
  // out = sum(partials) + b_out
  combine4_kernel<<<dim3(2048), 256, 0, stream>>>(
      (const unsigned short*)opart, b_out, out);
}